// Round 5
// baseline (103.305 us; speedup 1.0000x reference)
//
#include <hip/hip_runtime.h>
#include <math.h>

// PostProcess: B=16, Q=2048, C=2. SINGLE normal-launch kernel, grid = B*16 x 1024.
// R5 = verified R4 (48 us, passing) + two changes:
//  A) ff1-driven greedy scan: per chunk, diag VGPR (lane t = row 32c+t's word c,
//     the SAME memory word old STEP read via readlane(rr_t,c)). Scalar loop pops
//     only un-suppressed elements via ctz (~150 total vs 576 serial STEPs); the
//     rem accumulation moves off the serial chain into a branchless 32-term
//     predicated OR (same final rem by OR-commutativity). Selection order
//     (ascending t, skip suppressed) identical to verified STEP semantics.
//  B) 16 slices/image (grid 256): pure re-parameterization of the verified
//     round-robin gi loop (stride 256, start slice*16+wave); halves matrix wall
//     time. blk%8 == b%8 still holds (16%8==0): all slices+consumer on one XCD.
// R3's u32-key is permanently retired: 0x3F800000-0x3F333333 = 0x4CCCCD (23
// bits), +11 idx bits = 34 > 32 -- the key overflowed; exact u32 is impossible.
// ws: flags u32[256]@0 | mat u32[16][17408]@1024   (~1.12 MB)

#define QN     2048
#define NS     1024      // fast-path max valid boxes (E[M]=562, sd~20; M>NS ~23 sigma)
#define NSLICE 16
#define MATW   17408     // ragged u32 words/image = 64 * sum_{wb<16}(32-2wb)
#define MAGIC  0x5ca1ab1eu

#define REP32(X) X(0)X(1)X(2)X(3)X(4)X(5)X(6)X(7)X(8)X(9)X(10)X(11)X(12)X(13) \
                 X(14)X(15)X(16)X(17)X(18)X(19)X(20)X(21)X(22)X(23)X(24)X(25) \
                 X(26)X(27)X(28)X(29)X(30)X(31)

__device__ __forceinline__ int rb32(int wb) { return 64 * wb * (33 - wb); }

__device__ __forceinline__ unsigned long long shfl_xor_u64(unsigned long long x, int m) {
    int lo = __shfl_xor((int)(unsigned)(x & 0xffffffffull), m, 64);
    int hi = __shfl_xor((int)(unsigned)(x >> 32), m, 64);
    return ((unsigned long long)(unsigned)hi << 32) | (unsigned)lo;
}

// ascending key order == score desc, idx asc (stable); invalid -> tail.
__device__ __forceinline__ unsigned long long score_key(float2 l, int q, bool* valid_out) {
    float mx = fmaxf(l.x, l.y), mn = fminf(l.x, l.y);
    float e = expf(mn - mx);
    float score = 1.0f / (1.0f + e);                 // max softmax prob (exact ref order)
    bool valid = (l.x >= l.y) && (score >= 0.7f);    // argmax tie -> class 0
    *valid_out = valid;
    unsigned sbits = valid ? __float_as_uint(score) : 0u;
    return ((unsigned long long)(~sbits) << 32) | (unsigned)q;
}

__global__ __launch_bounds__(1024, 4) void kfused(
    const float* __restrict__ logits, const float* __restrict__ pboxes,
    const int* __restrict__ img_h_p, const int* __restrict__ img_w_p,
    unsigned* __restrict__ wflag, unsigned* __restrict__ wmat,
    float* __restrict__ out, int B)
{
    // fast path: skey u64[NS]@0 | sx1@8192 sy1@12288 sx2@16384 sy2@20480 sar@24576
    //            | sidxl u16[NS]@28672 | keepq u8[QN]@30720 | skm u32[32]@32768
    //            | sM@32896 | skeyB u64[NS]@33024 (ping-pong exchange)
    // fallback:  skeyF u64[QN]@0 (16KB, overlaps skey/sx1/sy1) | ssupp u8[QN]@16384
    __shared__ __align__(16) char smem[41216];
    unsigned long long* skey = (unsigned long long*)smem;
    float* sx1 = (float*)(smem + 8192);
    float* sy1 = (float*)(smem + 12288);
    float* sx2 = (float*)(smem + 16384);
    float* sy2 = (float*)(smem + 20480);
    float* sar = (float*)(smem + 24576);
    unsigned short* sidxl = (unsigned short*)(smem + 28672);
    unsigned char* keepq = (unsigned char*)(smem + 30720);
    unsigned* skm = (unsigned*)(smem + 32768);
    int* sMp = (int*)(smem + 32896);
    unsigned long long* skeyB = (unsigned long long*)(smem + 33024);

    const int blk = blockIdx.x;
    const int b = blk % B, slice = blk / B;
    const int tid = threadIdx.x, lane = tid & 63, wave = tid >> 6;
    const float sw = (float)(*img_w_p), sh = (float)(*img_h_p);

    if (tid == 0) *sMp = 0;
    keepq[tid] = 0; keepq[tid + 1024] = 0;
    if (tid < 32) skm[tid] = 0;
    __syncthreads();

    // ---- compact valid keys (ballot compaction; verified R4-R7) ----
    const unsigned long long lmask_lt = (1ull << lane) - 1ull;
#pragma unroll
    for (int qq = 0; qq < 2; ++qq) {
        int q = tid + qq * 1024;
        float2 l = ((const float2*)logits)[b * QN + q];
        bool valid;
        unsigned long long key = score_key(l, q, &valid);
        unsigned long long mb = __ballot(valid);
        int base = 0;
        if (lane == 0 && mb) base = atomicAdd(sMp, __popcll(mb));
        base = __shfl(base, 0, 64);
        if (valid) {
            int slot = base + __popcll(mb & lmask_lt);
            if (slot < NS) skey[slot] = key;
        }
    }
    __syncthreads();
    const int M = *sMp;

    if (M <= NS) {
        // ---- register bitonic sort of NS u64, 1 elem/thread (verified R4/R5) ----
        unsigned long long v = (tid < M) ? skey[tid] : ~0ull;
        __syncthreads();   // skey reused as exchange buffer
#pragma unroll
        for (int k = 2; k <= 64; k <<= 1) {
            bool dir = ((tid & k) == 0);
#pragma unroll
            for (int j = k >> 1; j > 0; j >>= 1) {
                unsigned long long o = shfl_xor_u64(v, j);
                bool takeMin = (dir == ((tid & j) == 0));
                v = ((v < o) == takeMin) ? v : o;
            }
        }
        int pp = 0;
        for (int k = 128; k <= NS; k <<= 1) {
            bool dir = ((tid & k) == 0);
            for (int j = k >> 1; j >= 64; j >>= 1) {
                unsigned long long* buf = pp ? skeyB : skey;
                pp ^= 1;
                buf[tid] = v;
                __syncthreads();
                unsigned long long o = buf[tid ^ j];
                bool takeMin = (dir == ((tid & j) == 0));
                v = ((v < o) == takeMin) ? v : o;
            }
#pragma unroll
            for (int j = 32; j > 0; j >>= 1) {
                unsigned long long o = shfl_xor_u64(v, j);
                bool takeMin = (dir == ((tid & j) == 0));
                v = ((v < o) == takeMin) ? v : o;
            }
        }
        // sorted SoA (padding slots zero -> iou 0)
        int qi = (int)((unsigned)v & 0xffffu);
        sidxl[tid] = (unsigned short)qi;
        float x1 = 0.f, y1 = 0.f, x2 = 0.f, y2 = 0.f, ar = 0.f;
        if (tid < M) {
            float4 pb = ((const float4*)pboxes)[b * QN + qi];
            x1 = (pb.x - 0.5f * pb.z) * sw;
            y1 = (pb.y - 0.5f * pb.w) * sh;
            x2 = (pb.x + 0.5f * pb.z) * sw;
            y2 = (pb.y + 0.5f * pb.w) * sh;
            ar = fmaxf(x2 - x1, 0.f) * fmaxf(y2 - y1, 0.f);
        }
        sx1[tid] = x1; sy1[tid] = y1; sx2[tid] = x2; sy2[tid] = y2; sar[tid] = ar;
        __syncthreads();

        // ---- matrix slice (verified R5-R7; 16 slices, stride 256) ----
        unsigned* mat = wmat + (long)b * MATW;
        const int NG = (M + 3) >> 2;
        const int W64 = (M + 63) >> 6;
        for (int gi = slice * 16 + wave; gi < NG; gi += 256) {
            const int g = gi << 2;
            const int nr = min(4, M - g);
            const int wb = g >> 6;
            const int rl = 32 - 2 * wb;
            float ax1[4], ay1[4], ax2[4], ay2[4], aar[4];
            int rbase[4];
#pragma unroll
            for (int r = 0; r < 4; ++r) {
                int i = g + min(r, nr - 1);
                ax1[r] = sx1[i]; ay1[r] = sy1[i];
                ax2[r] = sx2[i]; ay2[r] = sy2[i]; aar[r] = sar[i];
                rbase[r] = rb32(wb) + ((g + r) & 63) * rl;
            }
            for (int w = wb; w < W64; ++w) {
                int j = (w << 6) | lane;
                float bx1 = sx1[j], by1 = sy1[j], bx2 = sx2[j], by2 = sy2[j], bar = sar[j];
#pragma unroll
                for (int r = 0; r < 4; ++r) {
                    float ltx = fmaxf(ax1[r], bx1), lty = fmaxf(ay1[r], by1);
                    float rbx = fminf(ax2[r], bx2), rby = fminf(ay2[r], by2);
                    float wx = fmaxf(rbx - ltx, 0.f), wy = fmaxf(rby - lty, 0.f);
                    float inter = wx * wy;
                    float uni = aar[r] + bar - inter;       // exact ref op order
                    float iou = inter / fmaxf(uni, 1e-9f);  // exact IEEE div
                    bool sup = (iou > 0.5f) && (j > g + r);
                    unsigned long long bal = __ballot(sup);
                    if (lane == 0 && r < nr)
                        *(unsigned long long*)(mat + rbase[r] + 2 * (w - wb)) = bal;
                }
            }
        }
        __syncthreads();   // drains this block's matrix stores (vmcnt 0 at barrier)
        if (tid == 0)
            __hip_atomic_store(&wflag[b * NSLICE + slice], MAGIC,
                               __ATOMIC_RELEASE, __HIP_MEMORY_SCOPE_AGENT);
        if (slice != 0) return;    // producers done; consumer block continues

        // ---- consumer: spin for all 16 slices, then single-wave greedy scan ----
        if (wave == 0) {
            const unsigned* fp = &wflag[b * NSLICE + (lane & (NSLICE - 1))];
            for (;;) {
                unsigned f = (lane < NSLICE)
                    ? __hip_atomic_load(fp, __ATOMIC_ACQUIRE, __HIP_MEMORY_SCOPE_AGENT)
                    : MAGIC;
                if (__all(f == MAGIC)) break;
                __builtin_amdgcn_s_sleep(2);
            }
            // scan: lane L = removed-word L (rr named scalars, chunk prefetch);
            // diag lane t = row (32c+t)'s word c; ff1 loop pops only kept elems.
            const unsigned* gm = wmat + (long)b * MATW;
            unsigned rem = 0;
            const int Ms = __builtin_amdgcn_readfirstlane(M);
            const int C = (Ms + 31) >> 5;
            const int lam = min(tid, 31);
            unsigned diag = 0, diagN = 0;
#define DECLV(t) unsigned rr##t = 0u, nn##t = 0u;
            REP32(DECLV)
#undef DECLV
            if (C > 0) {
#define LD0(t) rr##t = gm[lam + t * 32];
                REP32(LD0)
#undef LD0
                diag = gm[lam * 32];           // c=0: wb=0, rl=32, word 0 of row lam
            }
            for (int c = 0; c < C; ++c) {
                if (c + 1 < C) {
                    int cn = c + 1, wbn = cn >> 1, rln = 32 - 2 * wbn;
                    int Lcn = min(max(tid, 2 * wbn), 31);
                    int rb0n = rb32(wbn) + ((cn & 1) << 5) * rln + (Lcn - 2 * wbn);
#define LDN(t) nn##t = gm[rb0n + t * rln];
                    REP32(LDN)
#undef LDN
                    // diag for chunk cn: row 32*cn+lam, word index cn-2*wbn
                    diagN = gm[rb32(wbn) + (((cn & 1) << 5) + lam) * rln + (cn - 2 * wbn)];
                }
                unsigned rw = (unsigned)__builtin_amdgcn_readlane((int)rem, c);
                int lim = min(32, Ms - (c << 5));
                unsigned limmask = (lim >= 32) ? 0xFFFFFFFFu : ((1u << lim) - 1u);
                unsigned avail = (~rw) & limmask;
                unsigned keepmask = 0;
                while (avail) {
                    int t = __builtin_ctz(avail);
                    keepmask |= (1u << t);
                    unsigned rword = (unsigned)__builtin_amdgcn_readlane((int)diag, t);
                    avail &= ~(1u << t);
                    avail &= ~rword;      // bit t of rword is 0 (j>i only), cleared above
                }
                // merge kept rows into rem (branchless; same final rem as serial OR)
#define MRG(t) rem |= (0u - ((keepmask >> t) & 1u)) & rr##t;
                REP32(MRG)
#undef MRG
                if (tid == 0) skm[c] = keepmask;
                if (c + 1 < C) {
#define CPYV(t) rr##t = nn##t;
                    REP32(CPYV)
#undef CPYV
                    diag = diagN;
                }
            }
        }
        __syncthreads();
        for (int s = tid; s < M; s += 1024)
            if ((skm[s >> 5] >> (s & 31)) & 1u) keepq[sidxl[s]] = 1;
        __syncthreads();
    } else {
        if (slice != 0) return;
        // ---- Fallback (M > NS, ~never): LDS sort + barrier greedy -> keepq ----
        unsigned long long* skeyF = (unsigned long long*)smem;
        unsigned char* ssupp = (unsigned char*)(smem + 16384);
        for (int q = tid; q < QN; q += 1024) {
            float2 l = ((const float2*)logits)[b * QN + q];
            bool valid;
            skeyF[q] = score_key(l, q, &valid);
        }
        __syncthreads();
        for (int k = 2; k <= QN; k <<= 1)
            for (int j = k >> 1; j > 0; j >>= 1) {
                int i = ((tid & ~(j - 1)) << 1) | (tid & (j - 1));
                int p = i | j;
                bool up = ((i & k) == 0);
                unsigned long long a = skeyF[i], c2 = skeyF[p];
                if ((a > c2) == up) { skeyF[i] = c2; skeyF[p] = a; }
                __syncthreads();
            }
        for (int s = tid; s < M; s += 1024) ssupp[s] = 0;
        __syncthreads();
        for (int i = 0; i < M; ++i) {
            __syncthreads();
            if (ssupp[i]) continue;
            int ia = (unsigned short)(unsigned)skeyF[i];
            float4 pa = ((const float4*)pboxes)[b * QN + ia];
            float ax1 = (pa.x - 0.5f * pa.z) * sw, ay1 = (pa.y - 0.5f * pa.w) * sh;
            float ax2 = (pa.x + 0.5f * pa.z) * sw, ay2 = (pa.y + 0.5f * pa.w) * sh;
            float areaA = fmaxf(ax2 - ax1, 0.f) * fmaxf(ay2 - ay1, 0.f);
            for (int jj = i + 1 + tid; jj < M; jj += 1024) {
                int jb = (unsigned short)(unsigned)skeyF[jj];
                float4 pq = ((const float4*)pboxes)[b * QN + jb];
                float bx1 = (pq.x - 0.5f * pq.z) * sw, by1 = (pq.y - 0.5f * pq.w) * sh;
                float bx2 = (pq.x + 0.5f * pq.z) * sw, by2 = (pq.y + 0.5f * pq.w) * sh;
                float ltx = fmaxf(ax1, bx1), lty = fmaxf(ay1, by1);
                float rbx = fminf(ax2, bx2), rby = fminf(ay2, by2);
                float wx = fmaxf(rbx - ltx, 0.f), wy = fmaxf(rby - lty, 0.f);
                float inter = wx * wy;
                float areaB = fmaxf(bx2 - bx1, 0.f) * fmaxf(by2 - by1, 0.f);
                float uni = areaA + areaB - inter;
                if (inter / fmaxf(uni, 1e-9f) > 0.5f) ssupp[jj] = 1;
            }
        }
        __syncthreads();
        for (int s = tid; s < M; s += 1024)
            if (!ssupp[s]) keepq[(unsigned short)(unsigned)skeyF[s]] = 1;
        __syncthreads();
    }

    // ---- epilogue: all outputs (d_out poisoned every call); consumer blocks only ----
    const long BQ = (long)B * QN;
#pragma unroll
    for (int qq = 0; qq < 2; ++qq) {
        int q = tid + qq * 1024;
        int base = b * QN + q;
        float2 l = ((const float2*)logits)[base];
        float e = expf(fminf(l.x, l.y) - fmaxf(l.x, l.y));
        float score = 1.0f / (1.0f + e);
        float4 pb = ((const float4*)pboxes)[base];
        float x1 = (pb.x - 0.5f * pb.z) * sw, y1 = (pb.y - 0.5f * pb.w) * sh;
        float x2 = (pb.x + 0.5f * pb.z) * sw, y2 = (pb.y + 0.5f * pb.w) * sh;
        int kp = keepq[q];
        out[base] = kp ? score : 0.f;
        out[BQ * 5 + base] = kp ? 1.f : 0.f;
        float4 ob;
        ob.x = kp ? truncf(x1) : 0.f;
        ob.y = kp ? truncf(y1) : 0.f;
        ob.z = kp ? truncf(x2) : 0.f;
        ob.w = kp ? truncf(y2) : 0.f;
        ((float4*)(out + BQ))[base] = ob;
    }
}

extern "C" void kernel_launch(void* const* d_in, const int* in_sizes, int n_in,
                              void* d_out, int out_size, void* d_ws, size_t ws_size,
                              hipStream_t stream) {
    const float* logits = (const float*)d_in[0];
    const float* pboxes = (const float*)d_in[1];
    const int*   img_h  = (const int*)d_in[2];
    const int*   img_w  = (const int*)d_in[3];
    float* out = (float*)d_out;
    const int B = in_sizes[0] / (QN * 2);   // 16

    char* ws = (char*)d_ws;                 // needs ~1.12 MB
    unsigned* wflag = (unsigned*)(ws + 0);
    unsigned* wmat  = (unsigned*)(ws + 1024);

    kfused<<<dim3(B * NSLICE), dim3(1024), 0, stream>>>(logits, pboxes, img_h, img_w,
                                                        wflag, wmat, out, B);
}

// Round 6
// 101.669 us; speedup vs baseline: 1.0161x; 1.0161x over previous
//
#include <hip/hip_runtime.h>
#include <math.h>

// PostProcess: B=16, Q=2048, C=2. R6: TWO stream-ordered kernels (phase ablation
// + removal of all inter-block coherence machinery).
//   kprep  (grid B*16 x 1024): compact + register bitonic sort + matrix slices
//          -> plain global stores of {M, sidxl, matrix}. NO flags, NO atomics,
//          NO spin. Kernel boundary on the stream provides device-wide
//          visibility (runtime release/acquire at dispatch boundary).
//   kfinal (grid B x 1024): ff1-driven greedy scan (verified R5) + scatter +
//          epilogue. Fallback (M>NS, ~never) fully self-contained here.
// Occupancy algebra on R0-R5 shows: parallel phase ~10us, consumer tail ~38us;
// the tail's only un-modeled component is the spin + agent-scope release/
// acquire cache machinery -- exactly what this split deletes. The two rocprof
// rows also give direct per-phase timing for the first time.
// ws: M u32[16]@0 | sidxl u16[16][1024]@1024 | mat u32[16][17408]@33792 (~1.1MB)

#define QN     2048
#define NS     1024      // fast-path max valid boxes (E[M]=562, sd~20; M>NS ~23 sigma)
#define NSLICE 16
#define MATW   17408     // ragged u32 words/image = 64 * sum_{wb<16}(32-2wb)
#define WSIDX  1024      // byte offset of sidxl area in ws
#define WSMAT  33792     // byte offset of matrix area in ws

__device__ __forceinline__ int rb32(int wb) { return 64 * wb * (33 - wb); }

__device__ __forceinline__ unsigned long long shfl_xor_u64(unsigned long long x, int m) {
    int lo = __shfl_xor((int)(unsigned)(x & 0xffffffffull), m, 64);
    int hi = __shfl_xor((int)(unsigned)(x >> 32), m, 64);
    return ((unsigned long long)(unsigned)hi << 32) | (unsigned)lo;
}

// ascending key order == score desc, idx asc (stable); invalid -> tail.
__device__ __forceinline__ unsigned long long score_key(float2 l, int q, bool* valid_out) {
    float mx = fmaxf(l.x, l.y), mn = fminf(l.x, l.y);
    float e = expf(mn - mx);
    float score = 1.0f / (1.0f + e);                 // max softmax prob (exact ref order)
    bool valid = (l.x >= l.y) && (score >= 0.7f);    // argmax tie -> class 0
    *valid_out = valid;
    unsigned sbits = valid ? __float_as_uint(score) : 0u;
    return ((unsigned long long)(~sbits) << 32) | (unsigned)q;
}

// ================= kernel 1: compact + sort + matrix =================
__global__ __launch_bounds__(1024) void kprep(
    const float* __restrict__ logits, const float* __restrict__ pboxes,
    const int* __restrict__ img_h_p, const int* __restrict__ img_w_p,
    unsigned* __restrict__ wsM, unsigned short* __restrict__ wsidx,
    unsigned* __restrict__ wmat, int B)
{
    // skey u64[NS]@0 | sx1@8192 sy1@12288 sx2@16384 sy2@20480 sar@24576
    // | sM@32896 | skeyB u64[NS]@33024 (ping-pong exchange)
    __shared__ __align__(16) char smem[41216];
    unsigned long long* skey = (unsigned long long*)smem;
    float* sx1 = (float*)(smem + 8192);
    float* sy1 = (float*)(smem + 12288);
    float* sx2 = (float*)(smem + 16384);
    float* sy2 = (float*)(smem + 20480);
    float* sar = (float*)(smem + 24576);
    int* sMp = (int*)(smem + 32896);
    unsigned long long* skeyB = (unsigned long long*)(smem + 33024);

    const int blk = blockIdx.x;
    const int b = blk % B, slice = blk / B;
    const int tid = threadIdx.x, lane = tid & 63, wave = tid >> 6;
    const float sw = (float)(*img_w_p), sh = (float)(*img_h_p);

    if (tid == 0) *sMp = 0;
    __syncthreads();

    // ---- compact valid keys (ballot compaction; verified R4-R7) ----
    const unsigned long long lmask_lt = (1ull << lane) - 1ull;
#pragma unroll
    for (int qq = 0; qq < 2; ++qq) {
        int q = tid + qq * 1024;
        float2 l = ((const float2*)logits)[b * QN + q];
        bool valid;
        unsigned long long key = score_key(l, q, &valid);
        unsigned long long mb = __ballot(valid);
        int base = 0;
        if (lane == 0 && mb) base = atomicAdd(sMp, __popcll(mb));
        base = __shfl(base, 0, 64);
        if (valid) {
            int slot = base + __popcll(mb & lmask_lt);
            if (slot < NS) skey[slot] = key;
        }
    }
    __syncthreads();
    const int M = *sMp;
    if (slice == 0 && tid == 0) wsM[b] = (unsigned)M;

    if (M > NS) return;   // kfinal handles the fallback end-to-end

    // ---- register bitonic sort of NS u64, 1 elem/thread (verified R4/R5) ----
    unsigned long long v = (tid < M) ? skey[tid] : ~0ull;
    __syncthreads();   // skey reused as exchange buffer
#pragma unroll
    for (int k = 2; k <= 64; k <<= 1) {
        bool dir = ((tid & k) == 0);
#pragma unroll
        for (int j = k >> 1; j > 0; j >>= 1) {
            unsigned long long o = shfl_xor_u64(v, j);
            bool takeMin = (dir == ((tid & j) == 0));
            v = ((v < o) == takeMin) ? v : o;
        }
    }
    int pp = 0;
    for (int k = 128; k <= NS; k <<= 1) {
        bool dir = ((tid & k) == 0);
        for (int j = k >> 1; j >= 64; j >>= 1) {
            unsigned long long* buf = pp ? skeyB : skey;
            pp ^= 1;
            buf[tid] = v;
            __syncthreads();
            unsigned long long o = buf[tid ^ j];
            bool takeMin = (dir == ((tid & j) == 0));
            v = ((v < o) == takeMin) ? v : o;
        }
#pragma unroll
        for (int j = 32; j > 0; j >>= 1) {
            unsigned long long o = shfl_xor_u64(v, j);
            bool takeMin = (dir == ((tid & j) == 0));
            v = ((v < o) == takeMin) ? v : o;
        }
    }
    // sorted SoA (padding slots zero -> iou 0)
    int qi = (int)((unsigned)v & 0xffffu);
    if (slice == 0) wsidx[b * NS + tid] = (unsigned short)qi;
    float x1 = 0.f, y1 = 0.f, x2 = 0.f, y2 = 0.f, ar = 0.f;
    if (tid < M) {
        float4 pb = ((const float4*)pboxes)[b * QN + qi];
        x1 = (pb.x - 0.5f * pb.z) * sw;
        y1 = (pb.y - 0.5f * pb.w) * sh;
        x2 = (pb.x + 0.5f * pb.z) * sw;
        y2 = (pb.y + 0.5f * pb.w) * sh;
        ar = fmaxf(x2 - x1, 0.f) * fmaxf(y2 - y1, 0.f);
    }
    sx1[tid] = x1; sy1[tid] = y1; sx2[tid] = x2; sy2[tid] = y2; sar[tid] = ar;
    __syncthreads();

    // ---- matrix slice (verified R5-R7; 16 slices, stride 256) ----
    unsigned* mat = wmat + (long)b * MATW;
    const int NG = (M + 3) >> 2;
    const int W64 = (M + 63) >> 6;
    for (int gi = slice * 16 + wave; gi < NG; gi += 256) {
        const int g = gi << 2;
        const int nr = min(4, M - g);
        const int wb = g >> 6;
        const int rl = 32 - 2 * wb;
        float ax1[4], ay1[4], ax2[4], ay2[4], aar[4];
        int rbase[4];
#pragma unroll
        for (int r = 0; r < 4; ++r) {
            int i = g + min(r, nr - 1);
            ax1[r] = sx1[i]; ay1[r] = sy1[i];
            ax2[r] = sx2[i]; ay2[r] = sy2[i]; aar[r] = sar[i];
            rbase[r] = rb32(wb) + ((g + r) & 63) * rl;
        }
        for (int w = wb; w < W64; ++w) {
            int j = (w << 6) | lane;
            float bx1 = sx1[j], by1 = sy1[j], bx2 = sx2[j], by2 = sy2[j], bar = sar[j];
#pragma unroll
            for (int r = 0; r < 4; ++r) {
                float ltx = fmaxf(ax1[r], bx1), lty = fmaxf(ay1[r], by1);
                float rbx = fminf(ax2[r], bx2), rby = fminf(ay2[r], by2);
                float wx = fmaxf(rbx - ltx, 0.f), wy = fmaxf(rby - lty, 0.f);
                float inter = wx * wy;
                float uni = aar[r] + bar - inter;       // exact ref op order
                float iou = inter / fmaxf(uni, 1e-9f);  // exact IEEE div
                bool sup = (iou > 0.5f) && (j > g + r);
                unsigned long long bal = __ballot(sup);
                if (lane == 0 && r < nr)
                    *(unsigned long long*)(mat + rbase[r] + 2 * (w - wb)) = bal;
            }
        }
    }
    // plain stores; visibility to kfinal guaranteed at kernel boundary
}

// ================= kernel 2: scan + scatter + epilogue =================
__global__ __launch_bounds__(1024) void kfinal(
    const float* __restrict__ logits, const float* __restrict__ pboxes,
    const int* __restrict__ img_h_p, const int* __restrict__ img_w_p,
    const unsigned* __restrict__ wsM, const unsigned short* __restrict__ wsidx,
    const unsigned* __restrict__ wmat, float* __restrict__ out, int B)
{
    // sidxl u16[NS]@28672 | keepq u8[QN]@30720 | skm u32[32]@32768
    // fallback: skeyF u64[QN]@0 (16KB) | ssupp u8[QN]@16384
    __shared__ __align__(16) char smem[32904];
    unsigned short* sidxl = (unsigned short*)(smem + 28672);
    unsigned char* keepq = (unsigned char*)(smem + 30720);
    unsigned* skm = (unsigned*)(smem + 32768);

    const int b = blockIdx.x;
    const int tid = threadIdx.x, wave = tid >> 6;
    const float sw = (float)(*img_w_p), sh = (float)(*img_h_p);

    keepq[tid] = 0; keepq[tid + 1024] = 0;
    if (tid < 32) skm[tid] = 0;
    const int M = (int)wsM[b];
    __syncthreads();

    if (M <= NS) {
        sidxl[tid] = wsidx[b * NS + tid];
        // ---- single-wave ff1-driven greedy scan (verified R5) ----
        if (wave == 0) {
            const unsigned* gm = wmat + (long)b * MATW;
            unsigned rem = 0;
            const int Ms = __builtin_amdgcn_readfirstlane(M);
            const int C = (Ms + 31) >> 5;
            const int lam = min(tid, 31);
            unsigned diag = 0, diagN = 0;
            unsigned rcur[32], rnxt[32];
            if (C > 0) {
#pragma unroll
                for (int t = 0; t < 32; ++t) rcur[t] = gm[lam + t * 32];
                diag = gm[lam * 32];           // c=0: wb=0, rl=32, word 0 of row lam
            }
            for (int c = 0; c < C; ++c) {
                if (c + 1 < C) {
                    int cn = c + 1, wbn = cn >> 1, rln = 32 - 2 * wbn;
                    int Lcn = min(max(tid, 2 * wbn), 31);
                    int rb0n = rb32(wbn) + ((cn & 1) << 5) * rln + (Lcn - 2 * wbn);
#pragma unroll
                    for (int t = 0; t < 32; ++t) rnxt[t] = gm[rb0n + t * rln];
                    // diag for chunk cn: row 32*cn+lam, word index cn-2*wbn
                    diagN = gm[rb32(wbn) + (((cn & 1) << 5) + lam) * rln + (cn - 2 * wbn)];
                }
                unsigned rw = (unsigned)__builtin_amdgcn_readlane((int)rem, c);
                int lim = min(32, Ms - (c << 5));
                unsigned limmask = (lim >= 32) ? 0xFFFFFFFFu : ((1u << lim) - 1u);
                unsigned avail = (~rw) & limmask;
                unsigned keepmask = 0;
                while (avail) {
                    int t = __builtin_ctz(avail);
                    keepmask |= (1u << t);
                    unsigned rword = (unsigned)__builtin_amdgcn_readlane((int)diag, t);
                    avail &= ~(1u << t);
                    avail &= ~rword;
                }
                // merge kept rows into rem (branchless; same final rem by OR-comm.)
#pragma unroll
                for (int t = 0; t < 32; ++t)
                    rem |= (0u - ((keepmask >> t) & 1u)) & rcur[t];
                if (tid == 0) skm[c] = keepmask;
                if (c + 1 < C) {
#pragma unroll
                    for (int t = 0; t < 32; ++t) rcur[t] = rnxt[t];
                    diag = diagN;
                }
            }
        }
        __syncthreads();
        for (int s = tid; s < M; s += 1024)
            if ((skm[s >> 5] >> (s & 31)) & 1u) keepq[sidxl[s]] = 1;
        __syncthreads();
    } else {
        // ---- Fallback (M > NS, ~never): self-contained LDS sort + greedy ----
        unsigned long long* skeyF = (unsigned long long*)smem;
        unsigned char* ssupp = (unsigned char*)(smem + 16384);
        for (int q = tid; q < QN; q += 1024) {
            float2 l = ((const float2*)logits)[b * QN + q];
            bool valid;
            skeyF[q] = score_key(l, q, &valid);
        }
        __syncthreads();
        for (int k = 2; k <= QN; k <<= 1)
            for (int j = k >> 1; j > 0; j >>= 1) {
                int i = ((tid & ~(j - 1)) << 1) | (tid & (j - 1));
                int p = i | j;
                bool up = ((i & k) == 0);
                unsigned long long a = skeyF[i], c2 = skeyF[p];
                if ((a > c2) == up) { skeyF[i] = c2; skeyF[p] = a; }
                __syncthreads();
            }
        for (int s = tid; s < M; s += 1024) ssupp[s] = 0;
        __syncthreads();
        for (int i = 0; i < M; ++i) {
            __syncthreads();
            if (ssupp[i]) continue;
            int ia = (unsigned short)(unsigned)skeyF[i];
            float4 pa = ((const float4*)pboxes)[b * QN + ia];
            float ax1 = (pa.x - 0.5f * pa.z) * sw, ay1 = (pa.y - 0.5f * pa.w) * sh;
            float ax2 = (pa.x + 0.5f * pa.z) * sw, ay2 = (pa.y + 0.5f * pa.w) * sh;
            float areaA = fmaxf(ax2 - ax1, 0.f) * fmaxf(ay2 - ay1, 0.f);
            for (int jj = i + 1 + tid; jj < M; jj += 1024) {
                int jb = (unsigned short)(unsigned)skeyF[jj];
                float4 pq = ((const float4*)pboxes)[b * QN + jb];
                float bx1 = (pq.x - 0.5f * pq.z) * sw, by1 = (pq.y - 0.5f * pq.w) * sh;
                float bx2 = (pq.x + 0.5f * pq.z) * sw, by2 = (pq.y + 0.5f * pq.w) * sh;
                float ltx = fmaxf(ax1, bx1), lty = fmaxf(ay1, by1);
                float rbx = fminf(ax2, bx2), rby = fminf(ay2, by2);
                float wx = fmaxf(rbx - ltx, 0.f), wy = fmaxf(rby - lty, 0.f);
                float inter = wx * wy;
                float areaB = fmaxf(bx2 - bx1, 0.f) * fmaxf(by2 - by1, 0.f);
                float uni = areaA + areaB - inter;
                if (inter / fmaxf(uni, 1e-9f) > 0.5f) ssupp[jj] = 1;
            }
        }
        __syncthreads();
        for (int s = tid; s < M; s += 1024)
            if (!ssupp[s]) keepq[(unsigned short)(unsigned)skeyF[s]] = 1;
        __syncthreads();
    }

    // ---- epilogue: all outputs (d_out poisoned every call) ----
    const long BQ = (long)B * QN;
#pragma unroll
    for (int qq = 0; qq < 2; ++qq) {
        int q = tid + qq * 1024;
        int base = b * QN + q;
        float2 l = ((const float2*)logits)[base];
        float e = expf(fminf(l.x, l.y) - fmaxf(l.x, l.y));
        float score = 1.0f / (1.0f + e);
        float4 pb = ((const float4*)pboxes)[base];
        float x1 = (pb.x - 0.5f * pb.z) * sw, y1 = (pb.y - 0.5f * pb.w) * sh;
        float x2 = (pb.x + 0.5f * pb.z) * sw, y2 = (pb.y + 0.5f * pb.w) * sh;
        int kp = keepq[q];
        out[base] = kp ? score : 0.f;
        out[BQ * 5 + base] = kp ? 1.f : 0.f;
        float4 ob;
        ob.x = kp ? truncf(x1) : 0.f;
        ob.y = kp ? truncf(y1) : 0.f;
        ob.z = kp ? truncf(x2) : 0.f;
        ob.w = kp ? truncf(y2) : 0.f;
        ((float4*)(out + BQ))[base] = ob;
    }
}

extern "C" void kernel_launch(void* const* d_in, const int* in_sizes, int n_in,
                              void* d_out, int out_size, void* d_ws, size_t ws_size,
                              hipStream_t stream) {
    const float* logits = (const float*)d_in[0];
    const float* pboxes = (const float*)d_in[1];
    const int*   img_h  = (const int*)d_in[2];
    const int*   img_w  = (const int*)d_in[3];
    float* out = (float*)d_out;
    const int B = in_sizes[0] / (QN * 2);   // 16

    char* ws = (char*)d_ws;                 // needs ~1.1 MB
    unsigned*       wsM   = (unsigned*)(ws + 0);
    unsigned short* wsidx = (unsigned short*)(ws + WSIDX);
    unsigned*       wmat  = (unsigned*)(ws + WSMAT);

    kprep<<<dim3(B * NSLICE), dim3(1024), 0, stream>>>(logits, pboxes, img_h, img_w,
                                                       wsM, wsidx, wmat, B);
    kfinal<<<dim3(B), dim3(1024), 0, stream>>>(logits, pboxes, img_h, img_w,
                                               wsM, wsidx, wmat, out, B);
}